// Round 5
// baseline (133.040 us; speedup 1.0000x reference)
//
#include <hip/hip_runtime.h>

// HDC encode + classify, wave-streaming, 2 dispatches total.
// Math: idx = clip(rint(x/20*20),0,20); cnt[b,t,l] = #channels at level l
//       smp[b,t,d] = ts[t,d] * sum_l cnt[b,t,l]*sig[l,d]
//       hv[b,d]    = sum_{j=0}^{124} prod_{i=0}^{3} smp[b,j+i,(d-3+i) mod D]
//       out[b,k]   = sum_d sign(hv[b,d]) * cw[k,d]
// All intermediates are exact small integers in fp32 -> order-free, sign exact.
//
// R3 lesson: contended same-line float atomics cost ~10 ns each, serialized.
// R4 lesson: harness overhead (268 MB ws re-poison = 40.6 us + restores) is
// the floor; what we still control is dispatch count + kernel bodies.
// This version fuses the partial-reduction into hdc_main via the
// last-block-done pattern: 4 per-batch counters on separate cache lines
// (164 time-spread atomics each), release fence + atomicAdd, last block
// acquires and reduces its batch's 10x164 partials into d_out.

#define D_     10000
#define NL_    21
#define B_     4
#define T_     128
#define C_     32
#define NC_    10
#define OPW_   61          // output columns per wave (64 lanes - 3 halo)
#define NTILE_ 164         // ceil(D / OPW) ; 164*61 = 10004
#define CNT_FLOATS_  (B_ * T_ * NL_)        // 10752
#define PART_FLOATS_ (B_ * NC_ * NTILE_)    // 6560

// ---------- kernel 1: per-(b,t) level histogram -> d_ws ; zero done-counters ----------
__global__ __launch_bounds__(128)
void hist_kernel(const float* __restrict__ x, float* __restrict__ cnt,
                 unsigned int* __restrict__ done) {
    const int t = threadIdx.x;     // one thread per t: rows private -> no atomics
    const int b = blockIdx.x;
    if (b == 0 && t < B_) done[t * 32] = 0u;   // padded counters, one line each
    float h[NL_];
    #pragma unroll
    for (int l = 0; l < NL_; ++l) h[l] = 0.0f;
    const float* xp = x + (b * T_ + t) * C_;
    #pragma unroll 8
    for (int c = 0; c < C_; ++c) {
        float r = rintf((xp[c] / 20.0f) * 20.0f);   // ref op order; round-half-even
        r = fminf(fmaxf(r, 0.0f), 20.0f);
        int lvl = (int)r;
        #pragma unroll
        for (int l = 0; l < NL_; ++l) h[l] += (l == lvl) ? 1.0f : 0.0f;
    }
    float* cp = cnt + (b * T_ + t) * NL_;
    #pragma unroll
    for (int l = 0; l < NL_; ++l) cp[l] = h[l];
}

// ---------- kernel 2: fused encode + classify + last-block reduction ----------
__global__ __launch_bounds__(256)
void hdc_main(const float* __restrict__ sig,
              const float* __restrict__ ts,
              const float* __restrict__ cw,
              const float* __restrict__ cnt,
              float* __restrict__ partial,
              unsigned int* __restrict__ done,
              float* __restrict__ out) {
    __shared__ float hv_s[4][64];
    __shared__ float red[NC_][17];   // +1 pad
    __shared__ int   is_last;

    const int tid  = threadIdx.x;
    const int lane = tid & 63;
    const int w    = tid >> 6;
    const int b    = blockIdx.x / NTILE_;
    const int tile = blockIdx.x % NTILE_;

    int dcol = tile * OPW_ - 3 + lane;          // column this lane streams
    if (dcol < 0)   dcol += D_;                 // roll wrap (tile 0 halo)
    if (dcol >= D_) dcol -= D_;                 // overhang lanes of last tile

    // per-lane signal slab: 21 regs, coalesced 256B/row loads
    float sr[NL_];
    #pragma unroll
    for (int l = 0; l < NL_; ++l) sr[l] = sig[l * D_ + dcol];

    // j-split across the 4 waves: [0,32) [32,63) [63,94) [94,125)
    int jo = (w == 0) ? 0 : (32 + 31 * (w - 1));
    int nj = (w == 0) ? 32 : 31;
    jo = __builtin_amdgcn_readfirstlane(jo);    // wave-uniform for scalar loads
    nj = __builtin_amdgcn_readfirstlane(nj);

    const float* cb = cnt + (b * T_ + jo) * NL_;   // uniform base
    const float* tp = ts + (size_t)jo * D_ + dcol;

    float a1 = 0.f, a2 = 0.f, a3 = 0.f, hv = 0.f;

    // pipeline fill: t = jo .. jo+2
    #pragma unroll
    for (int it = 0; it < 3; ++it) {
        const float* cr = cb + it * NL_;
        float s0 = 0.f, s1 = 0.f, s2 = 0.f;
        #pragma unroll
        for (int l = 0; l < 7; ++l) {
            s0 += cr[l]      * sr[l];
            s1 += cr[l + 7]  * sr[l + 7];
            s2 += cr[l + 14] * sr[l + 14];
        }
        float a0 = tp[(size_t)it * D_] * ((s0 + s1) + s2);
        a3 = a2; a2 = a1; a1 = a0;
    }
    // main loop: j = jo .. jo+nj-1  (t = j+3)
    #pragma unroll 4
    for (int j = 0; j < nj; ++j) {
        const int it = j + 3;
        const float* cr = cb + it * NL_;
        float s0 = 0.f, s1 = 0.f, s2 = 0.f;
        #pragma unroll
        for (int l = 0; l < 7; ++l) {
            s0 += cr[l]      * sr[l];
            s1 += cr[l + 7]  * sr[l + 7];
            s2 += cr[l + 14] * sr[l + 14];
        }
        float a0 = tp[(size_t)it * D_] * ((s0 + s1) + s2);
        float m3 = __shfl_up(a3, 3);
        float m2 = __shfl_up(a2, 2);
        float m1 = __shfl_up(a1, 1);
        hv += m3 * m2 * m1 * a0;
        a3 = a2; a2 = a1; a1 = a0;
    }

    hv_s[w][lane] = hv;
    __syncthreads();

    // every wave computes the same per-lane total
    float tot = hv_s[0][lane] + hv_s[1][lane] + hv_s[2][lane] + hv_s[3][lane];
    const int  dout  = tile * OPW_ + lane - 3;
    const bool valid = (lane >= 3) && (dout < D_);
    float enc = valid ? ((tot > 0.f) ? 1.f : -1.f) : 0.f;   // hard_quantize

    // classify: wave w handles classes k mod 4 == w; store partial (no contention)
    for (int k = w; k < NC_; k += 4) {
        float contrib = valid ? enc * cw[k * D_ + dout] : 0.f;
        #pragma unroll
        for (int m = 32; m >= 1; m >>= 1) contrib += __shfl_xor(contrib, m, 64);
        if (lane == 0) partial[(b * NC_ + k) * NTILE_ + tile] = contrib;
    }

    // ---- last-block-done reduction for this batch ----
    __threadfence();          // release: partial stores visible device-wide
    __syncthreads();          // all waves' stores drained before the atomic
    if (tid == 0) {
        unsigned int old = atomicAdd(&done[b * 32], 1u);
        is_last = (old == NTILE_ - 1) ? 1 : 0;
    }
    __syncthreads();
    if (is_last) {
        __threadfence();      // acquire: see all other blocks' partials
        if (tid < NC_ * 16) {
            const int k = tid >> 4, p = tid & 15;
            const float* rp = partial + (b * NC_ + k) * NTILE_;
            float acc = 0.0f;
            for (int i = p; i < NTILE_; i += 16) acc += rp[i];
            red[k][p] = acc;
        }
        __syncthreads();
        if (tid < NC_) {
            float s = 0.0f;
            #pragma unroll
            for (int p = 0; p < 16; ++p) s += red[tid][p];
            out[b * NC_ + tid] = s;
        }
    }
}

extern "C" void kernel_launch(void* const* d_in, const int* in_sizes, int n_in,
                              void* d_out, int out_size, void* d_ws, size_t ws_size,
                              hipStream_t stream) {
    const float* x   = (const float*)d_in[0];
    const float* sig = (const float*)d_in[1];
    // d_in[2] = channels_w: dead bind in the reference, intentionally unused
    const float* ts  = (const float*)d_in[3];
    const float* cw  = (const float*)d_in[4];
    float* out = (float*)d_out;
    float* cnt     = (float*)d_ws;                          // 10752 floats
    float* partial = (float*)d_ws + CNT_FLOATS_;            // 6560 floats
    unsigned int* done = (unsigned int*)(partial + PART_FLOATS_);  // 4 padded counters

    hist_kernel<<<B_, T_, 0, stream>>>(x, cnt, done);
    hdc_main<<<B_ * NTILE_, 256, 0, stream>>>(sig, ts, cw, cnt, partial, done, out);
}

// Round 6
// 88.785 us; speedup vs baseline: 1.4985x; 1.4985x over previous
//
#include <hip/hip_runtime.h>

// HDC encode + classify, 2 dispatches, no device-scope fences.
// Math: idx = clip(rint(x/20*20),0,20); cnt[b,t,l] = #channels at level l
//       smp[b,t,d] = ts[t,d] * sum_l cnt[b,t,l]*sig[l,d]
//       hv[b,d]    = sum_{j=0}^{124} prod_{i=0}^{3} smp[b,j+i,(d-3+i) mod D]
//       out[b,k]   = sum_d sign(hv[b,d]) * cw[k,d]
// All intermediates are exact small integers in fp32 -> order-free, sign exact.
//
// R3 lesson: contended same-line global float atomics ~10 ns each, serialized.
// R5 lesson: per-block __threadfence (agent scope) = buffer_wbl2/inv per block
//            -> L2 thrash (FETCH 5.7->10 MB), kernel 66 us. Dispatch boundary
//            is the only cheap cross-XCD coherence. Keep the 2-kernel shape.
// This round: histogram inlined per-block (redundant but ~1 us VALU), cutting
// the hist dispatch; cnt rows bulk-read from LDS into regs (ds_read_b128).

#define D_     10000
#define NL_    21
#define B_     4
#define T_     128
#define C_     32
#define NC_    10
#define OPW_   61          // output columns per wave (64 lanes - 3 halo)
#define NTILE_ 164         // ceil(D / OPW) ; 164*61 = 10004
#define CROW_  24          // cnt row stride (floats): 96 B, 16B-aligned for b128

// ---------- kernel 1: fused hist + encode + classify -> per-block partials ----------
__global__ __launch_bounds__(256)
void hdc_main(const float* __restrict__ x,
              const float* __restrict__ sig,
              const float* __restrict__ ts,
              const float* __restrict__ cw,
              float* __restrict__ partial) {
    __shared__ float cnt_s[T_][CROW_];   // 12288 B
    __shared__ float hv_s[4][64];        //  1024 B

    const int tid  = threadIdx.x;
    const int lane = tid & 63;
    const int w    = tid >> 6;
    const int b    = blockIdx.x / NTILE_;
    const int tile = blockIdx.x % NTILE_;

    int dcol = tile * OPW_ - 3 + lane;          // column this lane streams
    if (dcol < 0)   dcol += D_;                 // roll wrap (tile 0 halo)
    if (dcol >= D_) dcol -= D_;                 // overhang lanes of last tile

    // issue per-lane signal slab loads early (latency overlaps hist compute)
    float sr[NL_];
    #pragma unroll
    for (int l = 0; l < NL_; ++l) sr[l] = sig[l * D_ + dcol];

    // ---- inline per-(t) level histogram: threads 0..127, one t-row each ----
    if (tid < T_) {
        const float4* xp = (const float4*)(x + (b * T_ + tid) * C_);  // 128B-aligned row
        float h[NL_];
        #pragma unroll
        for (int l = 0; l < NL_; ++l) h[l] = 0.0f;
        #pragma unroll
        for (int q = 0; q < 8; ++q) {
            float4 v = xp[q];
            #pragma unroll
            for (int s = 0; s < 4; ++s) {
                float xv = (s == 0) ? v.x : (s == 1) ? v.y : (s == 2) ? v.z : v.w;
                float r = rintf((xv / 20.0f) * 20.0f);   // ref op order; round-half-even
                r = fminf(fmaxf(r, 0.0f), 20.0f);
                int lvl = (int)r;
                #pragma unroll
                for (int l = 0; l < NL_; ++l) h[l] += (l == lvl) ? 1.0f : 0.0f;
            }
        }
        #pragma unroll
        for (int l = 0; l < NL_; ++l) cnt_s[tid][l] = h[l];
    }
    __syncthreads();

    // j-split across the 4 waves: [0,32) [32,63) [63,94) [94,125)
    int jo = (w == 0) ? 0 : (32 + 31 * (w - 1));
    int nj = (w == 0) ? 32 : 31;
    jo = __builtin_amdgcn_readfirstlane(jo);
    nj = __builtin_amdgcn_readfirstlane(nj);

    const float* tp = ts + (size_t)jo * D_ + dcol;

    float a1 = 0.f, a2 = 0.f, a3 = 0.f, hv = 0.f;

    // pipeline fill: t = jo .. jo+2
    #pragma unroll
    for (int it = 0; it < 3; ++it) {
        float c[NL_];
        #pragma unroll
        for (int l = 0; l < NL_; ++l) c[l] = cnt_s[jo + it][l];  // b128-vectorized broadcast
        float s0 = 0.f, s1 = 0.f, s2 = 0.f;
        #pragma unroll
        for (int l = 0; l < 7; ++l) {
            s0 += c[l]      * sr[l];
            s1 += c[l + 7]  * sr[l + 7];
            s2 += c[l + 14] * sr[l + 14];
        }
        float a0 = tp[(size_t)it * D_] * ((s0 + s1) + s2);
        a3 = a2; a2 = a1; a1 = a0;
    }
    // main loop: j = jo .. jo+nj-1  (t = j+3)
    #pragma unroll 4
    for (int j = 0; j < nj; ++j) {
        const int it = jo + j + 3;
        float c[NL_];
        #pragma unroll
        for (int l = 0; l < NL_; ++l) c[l] = cnt_s[it][l];
        float s0 = 0.f, s1 = 0.f, s2 = 0.f;
        #pragma unroll
        for (int l = 0; l < 7; ++l) {
            s0 += c[l]      * sr[l];
            s1 += c[l + 7]  * sr[l + 7];
            s2 += c[l + 14] * sr[l + 14];
        }
        float a0 = tp[(size_t)(j + 3) * D_] * ((s0 + s1) + s2);
        float m3 = __shfl_up(a3, 3);
        float m2 = __shfl_up(a2, 2);
        float m1 = __shfl_up(a1, 1);
        hv += m3 * m2 * m1 * a0;
        a3 = a2; a2 = a1; a1 = a0;
    }

    hv_s[w][lane] = hv;
    __syncthreads();

    // every wave computes the same per-lane total
    float tot = hv_s[0][lane] + hv_s[1][lane] + hv_s[2][lane] + hv_s[3][lane];
    const int  dout  = tile * OPW_ + lane - 3;
    const bool valid = (lane >= 3) && (dout < D_);
    float enc = valid ? ((tot > 0.f) ? 1.f : -1.f) : 0.f;   // hard_quantize

    // classify: wave w handles classes k mod 4 == w; store partial (no contention)
    for (int k = w; k < NC_; k += 4) {
        float contrib = valid ? enc * cw[k * D_ + dout] : 0.f;
        #pragma unroll
        for (int m = 32; m >= 1; m >>= 1) contrib += __shfl_xor(contrib, m, 64);
        if (lane == 0) partial[(b * NC_ + k) * NTILE_ + tile] = contrib;
    }
}

// ---------- kernel 2: reduce partials -> out (dispatch boundary = coherence) ----------
__global__ __launch_bounds__(64)
void reduce_kernel(const float* __restrict__ partial, float* __restrict__ out) {
    const int row  = blockIdx.x;           // (b*NC + k), 40 rows
    const int lane = threadIdx.x;          // one wave
    const float* rp = partial + row * NTILE_;
    float acc = 0.0f;
    for (int i = lane; i < NTILE_; i += 64) acc += rp[i];
    #pragma unroll
    for (int m = 32; m >= 1; m >>= 1) acc += __shfl_xor(acc, m, 64);
    if (lane == 0) out[row] = acc;
}

extern "C" void kernel_launch(void* const* d_in, const int* in_sizes, int n_in,
                              void* d_out, int out_size, void* d_ws, size_t ws_size,
                              hipStream_t stream) {
    const float* x   = (const float*)d_in[0];
    const float* sig = (const float*)d_in[1];
    // d_in[2] = channels_w: dead bind in the reference, intentionally unused
    const float* ts  = (const float*)d_in[3];
    const float* cw  = (const float*)d_in[4];
    float* out = (float*)d_out;
    float* partial = (float*)d_ws;   // 40*164 = 6560 floats

    hdc_main<<<B_ * NTILE_, 256, 0, stream>>>(x, sig, ts, cw, partial);
    reduce_kernel<<<B_ * NC_, 64, 0, stream>>>(partial, out);
}